// Round 1
// baseline (656.903 us; speedup 1.0000x reference)
//
#include <hip/hip_runtime.h>
#include <cstdint>

using short8 = __attribute__((ext_vector_type(8))) short;
using f32x4  = __attribute__((ext_vector_type(4))) float;

// ---------- helpers ----------
__device__ __forceinline__ unsigned short bf16rne(float f) {
  unsigned int u = __float_as_uint(f);
  unsigned int r = u + 0x7fffu + ((u >> 16) & 1u);
  return (unsigned short)(r >> 16);
}

__device__ __forceinline__ void gl2lds16(const void* g, void* s) {
  // CK-style addrspace casts via uintptr_t
  auto gp = reinterpret_cast<const __attribute__((address_space(1))) unsigned int*>(
      reinterpret_cast<uintptr_t>(g));
  auto sp = reinterpret_cast<__attribute__((address_space(3))) unsigned int*>(
      (uint32_t)reinterpret_cast<uintptr_t>(s));
  __builtin_amdgcn_global_load_lds(gp, sp, 16, 0, 0);
}

__device__ __forceinline__ float fast_tanh(float x) {
  float e = __expf(2.0f * x);          // overflow->inf->tanh=1, underflow->-1: safe
  return 1.0f - 2.0f / (e + 1.0f);
}

// ---------- K0: fold Wq = W_k @ q  (bf16 [16][512]) ; Wvt = W_v^T (bf16 [1024][512]) ----------
__global__ void prep_kernel(const float* __restrict__ Wk, const float* __restrict__ q,
                            const float* __restrict__ Wv,
                            unsigned short* __restrict__ wqb,
                            unsigned short* __restrict__ wvt) {
  int idx = blockIdx.x * 256 + threadIdx.x;
  if (idx < 8192) {
    int n = idx >> 9, c = idx & 511;
    const float* wrow = Wk + (long)c * 1024 + n * 64;
    const float* qrow = q + n * 64;
    float s = 0.f;
    #pragma unroll 8
    for (int k = 0; k < 64; ++k) s += wrow[k] * qrow[k];
    wqb[n * 512 + c] = bf16rne(s);
  } else {
    int j = idx - 8192;
    if (j < 524288) {
      int col = j >> 9, c = j & 511;
      wvt[col * 512 + c] = bf16rne(Wv[(long)c * 1024 + col]);
    }
  }
}

// ---------- K1: kv fp32 -> bf16 ----------
__global__ void convert_kernel(const float4* __restrict__ x, ushort4* __restrict__ xb, int n4) {
  int stride = gridDim.x * blockDim.x;
  for (int i = blockIdx.x * blockDim.x + threadIdx.x; i < n4; i += stride) {
    float4 f = x[i];
    ushort4 o;
    o.x = bf16rne(f.x); o.y = bf16rne(f.y); o.z = bf16rne(f.z); o.w = bf16rne(f.w);
    xb[i] = o;
  }
}

// ---------- K2: dot[b][n][s] = xb @ Wq  (MFMA, M=128/block, N=16, K=512) ----------
__global__ __launch_bounds__(256) void dot_kernel(
    const unsigned short* __restrict__ xb, const unsigned short* __restrict__ wqb,
    float* __restrict__ dotbuf) {
  __shared__ __align__(16) unsigned short As[128 * 64];
  __shared__ __align__(16) unsigned short Ws[16 * 512];
  int tid = threadIdx.x;
  int l = tid & 63, w = tid >> 6;
  int lr = l >> 3, lc = l & 7;
  long row0 = (long)blockIdx.x * 128;

  // stage all of Wq once: inst (w,j) covers row n=w*4+j; lane l -> phys chunk l,
  // which holds logical chunk l ^ (n&7)
  for (int j = 0; j < 4; ++j) {
    int n = w * 4 + j;
    gl2lds16(wqb + n * 512 + ((l ^ (n & 7)) * 8), &Ws[n * 512]);
  }

  f32x4 acc[2];
  for (int mi = 0; mi < 2; ++mi) acc[mi] = f32x4{0.f, 0.f, 0.f, 0.f};

  for (int kb = 0; kb < 8; ++kb) {
    __syncthreads();
    for (int j = 0; j < 4; ++j) {
      int jj = w * 4 + j;
      int m = jj * 8 + lr;
      gl2lds16(xb + (row0 + m) * 512 + kb * 64 + ((lc ^ lr) * 8), &As[jj * 512]);
    }
    __syncthreads();
    #pragma unroll
    for (int k32 = 0; k32 < 2; ++k32) {
      int n = l & 15, qd = l >> 4;
      int cl = kb * 8 + k32 * 4 + qd;
      short8 bf = *(const short8*)&Ws[n * 512 + ((cl ^ (n & 7)) * 8)];
      int ch = k32 * 4 + qd;
      #pragma unroll
      for (int mi = 0; mi < 2; ++mi) {
        int m = w * 32 + mi * 16 + (l & 15);
        short8 af = *(const short8*)&As[m * 64 + ((ch ^ (l & 7)) * 8)];
        acc[mi] = __builtin_amdgcn_mfma_f32_16x16x32_bf16(af, bf, acc[mi], 0, 0, 0);
      }
    }
  }
  int n = l & 15, qd = l >> 4;
  for (int mi = 0; mi < 2; ++mi) {
    long rg = row0 + w * 32 + mi * 16 + qd * 4;
    long b = rg >> 12;
    long s = rg & 4095;
    *(f32x4*)&dotbuf[((b * 16 + n) << 12) + s] = acc[mi];
  }
}

// ---------- K3: softmax over s per (b,n), normalize in place ----------
__global__ __launch_bounds__(256) void softmax_kernel(float* __restrict__ dotbuf) {
  long bn = blockIdx.x;
  float4* p = (float4*)(dotbuf + bn * 4096);
  int tid = threadIdx.x;
  int l = tid & 63, w = tid >> 6;
  float4 v[4];
  float mx = -1e30f;
  #pragma unroll
  for (int i = 0; i < 4; ++i) {
    v[i] = p[tid + i * 256];
    mx = fmaxf(mx, fmaxf(fmaxf(v[i].x, v[i].y), fmaxf(v[i].z, v[i].w)));
  }
  for (int o = 32; o; o >>= 1) mx = fmaxf(mx, __shfl_xor(mx, o, 64));
  __shared__ float redm[4];
  __shared__ float reds[4];
  if (l == 0) redm[w] = mx;
  __syncthreads();
  mx = fmaxf(fmaxf(redm[0], redm[1]), fmaxf(redm[2], redm[3]));
  float s = 0.f;
  #pragma unroll
  for (int i = 0; i < 4; ++i) {
    v[i].x = __expf(v[i].x - mx); v[i].y = __expf(v[i].y - mx);
    v[i].z = __expf(v[i].z - mx); v[i].w = __expf(v[i].w - mx);
    s += v[i].x + v[i].y + v[i].z + v[i].w;
  }
  for (int o = 32; o; o >>= 1) s += __shfl_xor(s, o, 64);
  if (l == 0) reds[w] = s;
  __syncthreads();
  s = reds[0] + reds[1] + reds[2] + reds[3];
  float inv = 1.0f / s;
  #pragma unroll
  for (int i = 0; i < 4; ++i) {
    v[i].x *= inv; v[i].y *= inv; v[i].z *= inv; v[i].w *= inv;
    p[tid + i * 256] = v[i];
  }
}

// ---------- K4: fused value GEMM + tanh + weighted spatial reduce ----------
// grid (ct=8, rt=32, b=32), 128x128 tile, BK=64, 4 waves (2x2 of 64x64)
__global__ __launch_bounds__(256) void out_gemm_kernel(
    const unsigned short* __restrict__ xb, const unsigned short* __restrict__ wvt,
    const float* __restrict__ wn, const float* __restrict__ bv,
    float* __restrict__ out) {
  __shared__ __align__(16) unsigned short As[128 * 64];
  __shared__ __align__(16) unsigned short Bs[128 * 64];
  __shared__ float wlds[256];
  int tid = threadIdx.x;
  int l = tid & 63, w = tid >> 6;
  int wr = w >> 1, wc = w & 1;
  int lr = l >> 3, lc = l & 7;
  int ct = blockIdx.x, rt = blockIdx.y, b = blockIdx.z;
  long row0 = ((long)b << 12) + rt * 128;
  long col0 = (long)ct * 128;
  const unsigned short* Ag = xb + row0 * 512;
  const unsigned short* Bg = wvt + col0 * 512;

  f32x4 acc[4][4];
  #pragma unroll
  for (int mi = 0; mi < 4; ++mi)
    #pragma unroll
    for (int ni = 0; ni < 4; ++ni) acc[mi][ni] = f32x4{0.f, 0.f, 0.f, 0.f};

  for (int kb = 0; kb < 8; ++kb) {
    __syncthreads();
    for (int j = 0; j < 4; ++j) {
      int jj = w * 4 + j;
      int r = jj * 8 + lr;
      int goff = r * 512 + kb * 64 + (lc ^ lr) * 8;
      gl2lds16(Ag + goff, &As[jj * 512]);
      gl2lds16(Bg + goff, &Bs[jj * 512]);
    }
    __syncthreads();
    #pragma unroll
    for (int k32 = 0; k32 < 2; ++k32) {
      int ch = k32 * 4 + (l >> 4);
      short8 af[4], bfr[4];
      #pragma unroll
      for (int mi = 0; mi < 4; ++mi) {
        int m = wr * 64 + mi * 16 + (l & 15);
        af[mi] = *(const short8*)&As[m * 64 + ((ch ^ (l & 7)) * 8)];
      }
      #pragma unroll
      for (int ni = 0; ni < 4; ++ni) {
        int n = wc * 64 + ni * 16 + (l & 15);
        bfr[ni] = *(const short8*)&Bs[n * 64 + ((ch ^ (l & 7)) * 8)];
      }
      #pragma unroll
      for (int mi = 0; mi < 4; ++mi)
        #pragma unroll
        for (int ni = 0; ni < 4; ++ni)
          acc[mi][ni] = __builtin_amdgcn_mfma_f32_16x16x32_bf16(af[mi], bfr[ni], acc[mi][ni], 0, 0, 0);
    }
  }

  // epilogue: out[b,n,v] += sum_rows wn[b,n,s] * tanh(acc + bv)
  int head0 = ct * 2;
  __syncthreads();
  {
    int hh = tid >> 7, r = tid & 127;
    wlds[tid] = wn[(((long)b * 16 + head0 + hh) << 12) + rt * 128 + r];
  }
  __syncthreads();
  int ngl = head0 + wc;
  int v0 = l & 15, qd = l >> 4;
  float bias[4];
  #pragma unroll
  for (int ni = 0; ni < 4; ++ni) bias[ni] = bv[ngl * 64 + ni * 16 + v0];
  float res[4] = {0.f, 0.f, 0.f, 0.f};
  #pragma unroll
  for (int mi = 0; mi < 4; ++mi) {
    int rb = wr * 64 + mi * 16 + qd * 4;
    float w0 = wlds[wc * 128 + rb + 0];
    float w1 = wlds[wc * 128 + rb + 1];
    float w2 = wlds[wc * 128 + rb + 2];
    float w3 = wlds[wc * 128 + rb + 3];
    #pragma unroll
    for (int ni = 0; ni < 4; ++ni) {
      f32x4 c = acc[mi][ni];
      res[ni] += w0 * fast_tanh(c[0] + bias[ni]) + w1 * fast_tanh(c[1] + bias[ni])
               + w2 * fast_tanh(c[2] + bias[ni]) + w3 * fast_tanh(c[3] + bias[ni]);
    }
  }
  #pragma unroll
  for (int ni = 0; ni < 4; ++ni) {
    float v = res[ni];
    v += __shfl_xor(v, 16, 64);
    v += __shfl_xor(v, 32, 64);
    if (qd == 0) atomicAdd(&out[b * 1024 + ngl * 64 + ni * 16 + v0], v);
  }
}

// ---------- launch ----------
extern "C" void kernel_launch(void* const* d_in, const int* in_sizes, int n_in,
                              void* d_out, int out_size, void* d_ws, size_t ws_size,
                              hipStream_t stream) {
  const float* kv = (const float*)d_in[0];
  const float* Wk = (const float*)d_in[1];
  // d_in[2] = b_k : cancels under softmax, unused
  const float* Wv = (const float*)d_in[3];
  const float* bv = (const float*)d_in[4];
  const float* q  = (const float*)d_in[5];
  float* out = (float*)d_out;

  char* ws = (char*)d_ws;
  unsigned short* xb  = (unsigned short*)(ws);                         // 131072*512 bf16 = 128 MB
  unsigned short* wqb = (unsigned short*)(ws + 134217728);             // 16*512 bf16
  unsigned short* wvt = (unsigned short*)(ws + 134217728 + 16384);     // 1024*512 bf16 = 1 MB
  float* dotbuf = (float*)(ws + 134217728 + 16384 + 1048576);          // 32*16*4096 f32 = 8 MB

  hipMemsetAsync(d_out, 0, 32768 * sizeof(float), stream);
  prep_kernel<<<2081, 256, 0, stream>>>(Wk, q, Wv, wqb, wvt);
  convert_kernel<<<4096, 256, 0, stream>>>((const float4*)kv, (ushort4*)xb, 16777216);
  dot_kernel<<<1024, 256, 0, stream>>>(xb, wqb, dotbuf);
  softmax_kernel<<<512, 256, 0, stream>>>(dotbuf);
  out_gemm_kernel<<<dim3(8, 32, 32), 256, 0, stream>>>(xb, wvt, dotbuf, bv, out);
}

// Round 2
// 636.608 us; speedup vs baseline: 1.0319x; 1.0319x over previous
//
#include <hip/hip_runtime.h>
#include <cstdint>

using short8 = __attribute__((ext_vector_type(8))) short;
using f32x4  = __attribute__((ext_vector_type(4))) float;

// ---------- helpers ----------
__device__ __forceinline__ unsigned short bf16rne(float f) {
  unsigned int u = __float_as_uint(f);
  unsigned int r = u + 0x7fffu + ((u >> 16) & 1u);
  return (unsigned short)(r >> 16);
}

__device__ __forceinline__ void gl2lds16(const void* g, void* s) {
  auto gp = reinterpret_cast<const __attribute__((address_space(1))) unsigned int*>(
      reinterpret_cast<uintptr_t>(g));
  auto sp = reinterpret_cast<__attribute__((address_space(3))) unsigned int*>(
      (uint32_t)reinterpret_cast<uintptr_t>(s));
  __builtin_amdgcn_global_load_lds(gp, sp, 16, 0, 0);
}

__device__ __forceinline__ float fast_tanh(float x) {
  float e = __expf(2.0f * x);
  return 1.0f - 2.0f / (e + 1.0f);
}

// ---------- K0: fold Wq = W_k @ q (bf16 [16][512]); Wvt = W_v^T (bf16 [1024][512]) ----------
// blocks 0..31: fold (strided but tiny, L2-resident). blocks 32..159: 64x64 tiled transpose.
__global__ __launch_bounds__(256) void prep_kernel(
    const float* __restrict__ Wk, const float* __restrict__ q,
    const float* __restrict__ Wv,
    unsigned short* __restrict__ wqb, unsigned short* __restrict__ wvt) {
  __shared__ float T[64 * 65];
  int bid = blockIdx.x;
  if (bid < 32) {
    int idx = bid * 256 + threadIdx.x;   // 0..8191
    int n = idx >> 9, c = idx & 511;
    const float* wrow = Wk + (long)c * 1024 + n * 64;
    const float* qrow = q + n * 64;
    float s = 0.f;
    #pragma unroll 8
    for (int k = 0; k < 64; ++k) s += wrow[k] * qrow[k];
    wqb[n * 512 + c] = bf16rne(s);
  } else {
    int t = bid - 32;                    // 0..127
    int tc = t & 7, tl = t >> 3;         // c-tile (512/64), col-tile (1024/64)
    int c0 = tc * 64, l0 = tl * 64;
    int j = threadIdx.x & 63, i0 = threadIdx.x >> 6;
    #pragma unroll
    for (int ii = 0; ii < 16; ++ii) {
      int i = i0 * 16 + ii;
      T[i * 65 + j] = Wv[(long)(c0 + i) * 1024 + l0 + j];   // coalesced in j
    }
    __syncthreads();
    #pragma unroll
    for (int ii = 0; ii < 16; ++ii) {
      int jj = i0 * 16 + ii;
      wvt[(long)(l0 + jj) * 512 + c0 + j] = bf16rne(T[j * 65 + jj]);  // coalesced in j
    }
  }
}

// ---------- K2 (fused): kv fp32 -> bf16 (write xb) + dot = x @ Wq via MFMA ----------
// grid 1024, each block 128 rows. Per kb: reg-load fp32, cvt, ds_write swizzled As + store xb.
__global__ __launch_bounds__(256) void dot_kernel(
    const float* __restrict__ kv, const unsigned short* __restrict__ wqb,
    unsigned short* __restrict__ xb, float* __restrict__ dotbuf) {
  __shared__ __align__(16) unsigned short As[128 * 64];
  __shared__ __align__(16) unsigned short Ws[16 * 512];
  int tid = threadIdx.x;
  int l = tid & 63, w = tid >> 6;
  long row0 = (long)blockIdx.x * 128;

  // stage all of Wq once: phys chunk l holds logical chunk l ^ (n&7)
  for (int j = 0; j < 4; ++j) {
    int n = w * 4 + j;
    gl2lds16(wqb + n * 512 + ((l ^ (n & 7)) * 8), &Ws[n * 512]);
  }

  f32x4 acc[2];
  for (int mi = 0; mi < 2; ++mi) acc[mi] = f32x4{0.f, 0.f, 0.f, 0.f};

  for (int kb = 0; kb < 8; ++kb) {
    // load 128x64 fp32 chunk into regs, convert, write xb
    float4 fa[4][2];
    short8 ha[4];
    #pragma unroll
    for (int it = 0; it < 4; ++it) {
      int idx = it * 256 + tid;          // 0..1023
      int r = idx >> 3, c8 = idx & 7;    // row, 8-float chunk
      const float4* src = (const float4*)&kv[(row0 + r) * 512 + kb * 64 + c8 * 8];
      fa[it][0] = src[0];
      fa[it][1] = src[1];
      short8 h;
      h[0] = bf16rne(fa[it][0].x); h[1] = bf16rne(fa[it][0].y);
      h[2] = bf16rne(fa[it][0].z); h[3] = bf16rne(fa[it][0].w);
      h[4] = bf16rne(fa[it][1].x); h[5] = bf16rne(fa[it][1].y);
      h[6] = bf16rne(fa[it][1].z); h[7] = bf16rne(fa[it][1].w);
      ha[it] = h;
      *(short8*)&xb[(row0 + r) * 512 + kb * 64 + c8 * 8] = h;
    }
    __syncthreads();   // previous iter's frag reads done (and Ws drained on kb=0)
    #pragma unroll
    for (int it = 0; it < 4; ++it) {
      int idx = it * 256 + tid;
      int r = idx >> 3, c8 = idx & 7;
      *(short8*)&As[r * 64 + ((c8 ^ (r & 7)) * 8)] = ha[it];   // swizzled store
    }
    __syncthreads();
    #pragma unroll
    for (int k32 = 0; k32 < 2; ++k32) {
      int n = l & 15, qd = l >> 4;
      int cl = kb * 8 + k32 * 4 + qd;
      short8 bf = *(const short8*)&Ws[n * 512 + ((cl ^ (n & 7)) * 8)];
      int ch = k32 * 4 + qd;
      #pragma unroll
      for (int mi = 0; mi < 2; ++mi) {
        int m = w * 32 + mi * 16 + (l & 15);
        short8 af = *(const short8*)&As[m * 64 + ((ch ^ (l & 7)) * 8)];
        acc[mi] = __builtin_amdgcn_mfma_f32_16x16x32_bf16(af, bf, acc[mi], 0, 0, 0);
      }
    }
    __syncthreads();   // frag reads done before next iter's ds_write
  }
  int n = l & 15, qd = l >> 4;
  for (int mi = 0; mi < 2; ++mi) {
    long rg = row0 + w * 32 + mi * 16 + qd * 4;
    long b = rg >> 12;
    long s = rg & 4095;
    *(f32x4*)&dotbuf[((b * 16 + n) << 12) + s] = acc[mi];
  }
}

// ---------- K3: softmax over s per (b,n), normalize in place ----------
__global__ __launch_bounds__(256) void softmax_kernel(float* __restrict__ dotbuf) {
  long bn = blockIdx.x;
  float4* p = (float4*)(dotbuf + bn * 4096);
  int tid = threadIdx.x;
  int l = tid & 63, w = tid >> 6;
  float4 v[4];
  float mx = -1e30f;
  #pragma unroll
  for (int i = 0; i < 4; ++i) {
    v[i] = p[tid + i * 256];
    mx = fmaxf(mx, fmaxf(fmaxf(v[i].x, v[i].y), fmaxf(v[i].z, v[i].w)));
  }
  for (int o = 32; o; o >>= 1) mx = fmaxf(mx, __shfl_xor(mx, o, 64));
  __shared__ float redm[4];
  __shared__ float reds[4];
  if (l == 0) redm[w] = mx;
  __syncthreads();
  mx = fmaxf(fmaxf(redm[0], redm[1]), fmaxf(redm[2], redm[3]));
  float s = 0.f;
  #pragma unroll
  for (int i = 0; i < 4; ++i) {
    v[i].x = __expf(v[i].x - mx); v[i].y = __expf(v[i].y - mx);
    v[i].z = __expf(v[i].z - mx); v[i].w = __expf(v[i].w - mx);
    s += v[i].x + v[i].y + v[i].z + v[i].w;
  }
  for (int o = 32; o; o >>= 1) s += __shfl_xor(s, o, 64);
  if (l == 0) reds[w] = s;
  __syncthreads();
  s = reds[0] + reds[1] + reds[2] + reds[3];
  float inv = 1.0f / s;
  #pragma unroll
  for (int i = 0; i < 4; ++i) {
    v[i].x *= inv; v[i].y *= inv; v[i].z *= inv; v[i].w *= inv;
    p[tid + i * 256] = v[i];
  }
}

// ---------- K4: fused value GEMM + tanh + weighted spatial reduce ----------
// 8192 blocks, XCD-swizzled so the 8 ct-blocks sharing one A-tile sit on ONE XCD,
// temporally adjacent (ids spaced 8): id = (g>>3)<<6 | ct<<3 | (g&7).
__global__ __launch_bounds__(256) void out_gemm_kernel(
    const unsigned short* __restrict__ xb, const unsigned short* __restrict__ wvt,
    const float* __restrict__ wn, const float* __restrict__ bv,
    float* __restrict__ out) {
  __shared__ __align__(16) unsigned short As[128 * 64];
  __shared__ __align__(16) unsigned short Bs[128 * 64];
  __shared__ float wlds[256];
  int tid = threadIdx.x;
  int l = tid & 63, w = tid >> 6;
  int wr = w >> 1, wc = w & 1;
  int lr = l >> 3, lc = l & 7;

  int id = blockIdx.x;
  int ct = (id >> 3) & 7;
  int g  = (id & 7) | ((id >> 6) << 3);   // 0..1023 : (rt,b) group, same-XCD members
  int rt = g & 31;
  int b  = g >> 5;

  long row0 = ((long)b << 12) + rt * 128;
  long col0 = (long)ct * 128;
  const unsigned short* Ag = xb + row0 * 512;
  const unsigned short* Bg = wvt + col0 * 512;

  f32x4 acc[4][4];
  #pragma unroll
  for (int mi = 0; mi < 4; ++mi)
    #pragma unroll
    for (int ni = 0; ni < 4; ++ni) acc[mi][ni] = f32x4{0.f, 0.f, 0.f, 0.f};

  for (int kb = 0; kb < 8; ++kb) {
    __syncthreads();
    for (int j = 0; j < 4; ++j) {
      int jj = w * 4 + j;
      int r = jj * 8 + lr;
      int goff = r * 512 + kb * 64 + (lc ^ lr) * 8;
      gl2lds16(Ag + goff, &As[jj * 512]);
      gl2lds16(Bg + goff, &Bs[jj * 512]);
    }
    __syncthreads();
    #pragma unroll
    for (int k32 = 0; k32 < 2; ++k32) {
      int ch = k32 * 4 + (l >> 4);
      short8 af[4], bfr[4];
      #pragma unroll
      for (int mi = 0; mi < 4; ++mi) {
        int m = wr * 64 + mi * 16 + (l & 15);
        af[mi] = *(const short8*)&As[m * 64 + ((ch ^ (l & 7)) * 8)];
      }
      #pragma unroll
      for (int ni = 0; ni < 4; ++ni) {
        int n = wc * 64 + ni * 16 + (l & 15);
        bfr[ni] = *(const short8*)&Bs[n * 64 + ((ch ^ (l & 7)) * 8)];
      }
      #pragma unroll
      for (int mi = 0; mi < 4; ++mi)
        #pragma unroll
        for (int ni = 0; ni < 4; ++ni)
          acc[mi][ni] = __builtin_amdgcn_mfma_f32_16x16x32_bf16(af[mi], bfr[ni], acc[mi][ni], 0, 0, 0);
    }
  }

  // epilogue: out[b,n,v] += sum_rows wn[b,n,s] * tanh(acc + bv)
  int head0 = ct * 2;
  __syncthreads();
  {
    int hh = tid >> 7, r = tid & 127;
    wlds[tid] = wn[(((long)b * 16 + head0 + hh) << 12) + rt * 128 + r];
  }
  __syncthreads();
  int ngl = head0 + wc;
  int v0 = l & 15, qd = l >> 4;
  float bias[4];
  #pragma unroll
  for (int ni = 0; ni < 4; ++ni) bias[ni] = bv[ngl * 64 + ni * 16 + v0];
  float res[4] = {0.f, 0.f, 0.f, 0.f};
  #pragma unroll
  for (int mi = 0; mi < 4; ++mi) {
    int rb = wr * 64 + mi * 16 + qd * 4;
    float w0 = wlds[wc * 128 + rb + 0];
    float w1 = wlds[wc * 128 + rb + 1];
    float w2 = wlds[wc * 128 + rb + 2];
    float w3 = wlds[wc * 128 + rb + 3];
    #pragma unroll
    for (int ni = 0; ni < 4; ++ni) {
      f32x4 c = acc[mi][ni];
      res[ni] += w0 * fast_tanh(c[0] + bias[ni]) + w1 * fast_tanh(c[1] + bias[ni])
               + w2 * fast_tanh(c[2] + bias[ni]) + w3 * fast_tanh(c[3] + bias[ni]);
    }
  }
  #pragma unroll
  for (int ni = 0; ni < 4; ++ni) {
    float v = res[ni];
    v += __shfl_xor(v, 16, 64);
    v += __shfl_xor(v, 32, 64);
    if (qd == 0) atomicAdd(&out[b * 1024 + ngl * 64 + ni * 16 + v0], v);
  }
}

// ---------- launch ----------
extern "C" void kernel_launch(void* const* d_in, const int* in_sizes, int n_in,
                              void* d_out, int out_size, void* d_ws, size_t ws_size,
                              hipStream_t stream) {
  const float* kv = (const float*)d_in[0];
  const float* Wk = (const float*)d_in[1];
  // d_in[2] = b_k : constant over softmax axis -> cancels, unused
  const float* Wv = (const float*)d_in[3];
  const float* bv = (const float*)d_in[4];
  const float* q  = (const float*)d_in[5];
  float* out = (float*)d_out;

  char* ws = (char*)d_ws;
  unsigned short* xb  = (unsigned short*)(ws);                       // 128 MB
  unsigned short* wqb = (unsigned short*)(ws + 134217728);           // 16 KB
  unsigned short* wvt = (unsigned short*)(ws + 134217728 + 16384);   // 1 MB
  float* dotbuf = (float*)(ws + 134217728 + 16384 + 1048576);        // 8 MB

  hipMemsetAsync(d_out, 0, 32768 * sizeof(float), stream);
  prep_kernel<<<160, 256, 0, stream>>>(Wk, q, Wv, wqb, wvt);
  dot_kernel<<<1024, 256, 0, stream>>>(kv, wqb, xb, dotbuf);
  softmax_kernel<<<512, 256, 0, stream>>>(dotbuf);
  out_gemm_kernel<<<8192, 256, 0, stream>>>(xb, wvt, dotbuf, bv, out);
}

// Round 3
// 578.617 us; speedup vs baseline: 1.1353x; 1.1002x over previous
//
#include <hip/hip_runtime.h>
#include <cstdint>

using short8 = __attribute__((ext_vector_type(8))) short;
using f32x4  = __attribute__((ext_vector_type(4))) float;

// ---------- helpers ----------
__device__ __forceinline__ unsigned short bf16rne(float f) {
  unsigned int u = __float_as_uint(f);
  unsigned int r = u + 0x7fffu + ((u >> 16) & 1u);
  return (unsigned short)(r >> 16);
}

__device__ __forceinline__ void gl2lds16(const void* g, void* s) {
  auto gp = reinterpret_cast<const __attribute__((address_space(1))) unsigned int*>(
      reinterpret_cast<uintptr_t>(g));
  auto sp = reinterpret_cast<__attribute__((address_space(3))) unsigned int*>(
      (uint32_t)reinterpret_cast<uintptr_t>(s));
  __builtin_amdgcn_global_load_lds(gp, sp, 16, 0, 0);
}

__device__ __forceinline__ float fast_tanh(float x) {
  float e = __expf(2.0f * x);
  return 1.0f - 2.0f / (e + 1.0f);
}

// ---------- K0: fold Wq = W_k @ q (bf16 [16][512]); Wvt = W_v^T (bf16 [1024][512]) ----------
__global__ __launch_bounds__(256) void prep_kernel(
    const float* __restrict__ Wk, const float* __restrict__ q,
    const float* __restrict__ Wv,
    unsigned short* __restrict__ wqb, unsigned short* __restrict__ wvt) {
  __shared__ float T[64 * 65];
  int bid = blockIdx.x;
  if (bid < 32) {
    int idx = bid * 256 + threadIdx.x;   // 0..8191
    int n = idx >> 9, c = idx & 511;
    const float* wrow = Wk + (long)c * 1024 + n * 64;
    const float* qrow = q + n * 64;
    float s = 0.f;
    #pragma unroll 8
    for (int k = 0; k < 64; ++k) s += wrow[k] * qrow[k];
    wqb[n * 512 + c] = bf16rne(s);
  } else {
    int t = bid - 32;                    // 0..127
    int tc = t & 7, tl = t >> 3;
    int c0 = tc * 64, l0 = tl * 64;
    int j = threadIdx.x & 63, i0 = threadIdx.x >> 6;
    #pragma unroll
    for (int ii = 0; ii < 16; ++ii) {
      int i = i0 * 16 + ii;
      T[i * 65 + j] = Wv[(long)(c0 + i) * 1024 + l0 + j];
    }
    __syncthreads();
    #pragma unroll
    for (int ii = 0; ii < 16; ++ii) {
      int jj = i0 * 16 + ii;
      wvt[(long)(l0 + jj) * 512 + c0 + j] = bf16rne(T[j * 65 + jj]);
    }
  }
}

// ---------- K2: fused cvt + dot, 1-barrier async pipeline ----------
// block = 128 rows; stage kv f32 via global_load_lds (double-buffered, BK=64);
// ds_read f32 frags -> cvt bf16 once in regs -> {store xb, MFMA dot}.
__global__ __launch_bounds__(256) void dot_kernel(
    const float* __restrict__ kv, const unsigned short* __restrict__ wqb,
    unsigned short* __restrict__ xb, float* __restrict__ dotbuf) {
  __shared__ __align__(16) float AsF[2][128 * 64];          // 2 x 32 KB
  __shared__ __align__(16) unsigned short Ws[16 * 512];     // 16 KB
  int tid = threadIdx.x, l = tid & 63, w = tid >> 6;
  long row0 = (long)blockIdx.x * 128;
  int qd = l >> 4, lm = l & 15;

  // stage Wq once (8-chunk XOR layout, phys chunk p holds logical p ^ (n&7))
  for (int j = 0; j < 4; ++j) {
    int n = w * 4 + j;
    gl2lds16(wqb + n * 512 + ((l ^ (n & 7)) * 8), &Ws[n * 512]);
  }

  auto dmaA = [&](int it, int buf) {
    #pragma unroll
    for (int j = 0; j < 8; ++j) {
      int g = (w * 8 + j) * 64 + l;       // phys 16B-granule index
      int r = g >> 4, c = g & 15;
      int cc = c ^ (r & 14);              // even-bit XOR keeps 8-f32 frags contiguous
      gl2lds16(kv + (row0 + r) * 512 + it * 64 + cc * 4, &AsF[buf][(w * 8 + j) * 256]);
    }
  };

  f32x4 acc[2];
  acc[0] = f32x4{0.f, 0.f, 0.f, 0.f};
  acc[1] = f32x4{0.f, 0.f, 0.f, 0.f};

  dmaA(0, 0);
  for (int it = 0; it < 8; ++it) {
    __syncthreads();                       // drains DMA(it); prior frag reads done
    if (it < 7) dmaA(it + 1, (it + 1) & 1);
    const float* base = &AsF[it & 1][0];
    #pragma unroll
    for (int mi = 0; mi < 2; ++mi) {
      int m = w * 32 + mi * 16 + lm;
      int s = m & 14;
      #pragma unroll
      for (int k32 = 0; k32 < 2; ++k32) {
        int fc = k32 * 8 + qd * 2;
        float4 fa = *(const float4*)&base[(m * 16 + (fc ^ s)) * 4];
        float4 fb = *(const float4*)&base[(m * 16 + ((fc + 1) ^ s)) * 4];
        short8 h;
        h[0] = bf16rne(fa.x); h[1] = bf16rne(fa.y); h[2] = bf16rne(fa.z); h[3] = bf16rne(fa.w);
        h[4] = bf16rne(fb.x); h[5] = bf16rne(fb.y); h[6] = bf16rne(fb.z); h[7] = bf16rne(fb.w);
        *(short8*)&xb[(row0 + m) * 512 + it * 64 + k32 * 32 + qd * 8] = h;
        int cl = it * 8 + k32 * 4 + qd;
        short8 bfrag = *(const short8*)&Ws[lm * 512 + ((cl ^ (lm & 7)) * 8)];
        acc[mi] = __builtin_amdgcn_mfma_f32_16x16x32_bf16(h, bfrag, acc[mi], 0, 0, 0);
      }
    }
  }
  #pragma unroll
  for (int mi = 0; mi < 2; ++mi) {
    long rg = row0 + w * 32 + mi * 16 + qd * 4;
    long b = rg >> 12;
    long s = rg & 4095;
    *(f32x4*)&dotbuf[((b * 16 + lm) << 12) + s] = acc[mi];
  }
}

// ---------- K3: softmax over s per (b,n), normalize in place ----------
__global__ __launch_bounds__(256) void softmax_kernel(float* __restrict__ dotbuf) {
  long bn = blockIdx.x;
  float4* p = (float4*)(dotbuf + bn * 4096);
  int tid = threadIdx.x;
  int l = tid & 63, w = tid >> 6;
  float4 v[4];
  float mx = -1e30f;
  #pragma unroll
  for (int i = 0; i < 4; ++i) {
    v[i] = p[tid + i * 256];
    mx = fmaxf(mx, fmaxf(fmaxf(v[i].x, v[i].y), fmaxf(v[i].z, v[i].w)));
  }
  for (int o = 32; o; o >>= 1) mx = fmaxf(mx, __shfl_xor(mx, o, 64));
  __shared__ float redm[4];
  __shared__ float reds[4];
  if (l == 0) redm[w] = mx;
  __syncthreads();
  mx = fmaxf(fmaxf(redm[0], redm[1]), fmaxf(redm[2], redm[3]));
  float s = 0.f;
  #pragma unroll
  for (int i = 0; i < 4; ++i) {
    v[i].x = __expf(v[i].x - mx); v[i].y = __expf(v[i].y - mx);
    v[i].z = __expf(v[i].z - mx); v[i].w = __expf(v[i].w - mx);
    s += v[i].x + v[i].y + v[i].z + v[i].w;
  }
  for (int o = 32; o; o >>= 1) s += __shfl_xor(s, o, 64);
  if (l == 0) reds[w] = s;
  __syncthreads();
  s = reds[0] + reds[1] + reds[2] + reds[3];
  float inv = 1.0f / s;
  #pragma unroll
  for (int i = 0; i < 4; ++i) {
    v[i].x *= inv; v[i].y *= inv; v[i].z *= inv; v[i].w *= inv;
    p[tid + i * 256] = v[i];
  }
}

// ---------- K4: value GEMM + tanh + weighted reduce; 256x128 tile, 64x128/wave,
// BK=32 double-buffered, 1 barrier/iter. Pair-line swizzle: two 64B rows share a
// 128B line; phys sub = logical sub ^ (line&7) -> 2-way-max bank aliasing (free). ----------
__global__ __launch_bounds__(256, 2) void out_gemm_kernel(
    const unsigned short* __restrict__ xb, const unsigned short* __restrict__ wvt,
    const float* __restrict__ wn, const float* __restrict__ bv,
    float* __restrict__ out) {
  __shared__ __align__(16) unsigned short As[2][8192];   // 2 x 256r x 32k
  __shared__ __align__(16) unsigned short Bs[2][4096];   // 2 x 128n x 32k
  __shared__ float wlds[512];
  int tid = threadIdx.x, l = tid & 63, w = tid >> 6;
  int qd = l >> 4, lm = l & 15;

  int id = blockIdx.x;                    // XCD swizzle: same (rt,b), all 8 ct -> same XCD
  int ct = (id >> 3) & 7;
  int g = (id & 7) | ((id >> 6) << 3);    // 0..511
  int rt = g & 15, b = g >> 4;
  long row0 = ((long)b << 12) + rt * 256;
  const unsigned short* Ag = xb + row0 * 512;
  const unsigned short* Bg = wvt + (long)ct * 128 * 512;

  auto dma = [&](int it, int buf) {
    #pragma unroll
    for (int j = 0; j < 4; ++j) {
      int pl = (w * 4 + j) * 64 + l;
      int r2 = pl >> 3, sub = (pl & 7) ^ (r2 & 7);
      int r = r2 * 2 + (sub >> 2), c = sub & 3;
      gl2lds16(Ag + r * 512 + it * 32 + c * 8, &As[buf][(w * 4 + j) * 512]);
    }
    #pragma unroll
    for (int j = 0; j < 2; ++j) {
      int pl = (w * 2 + j) * 64 + l;
      int r2 = pl >> 3, sub = (pl & 7) ^ (r2 & 7);
      int r = r2 * 2 + (sub >> 2), c = sub & 3;
      gl2lds16(Bg + r * 512 + it * 32 + c * 8, &Bs[buf][(w * 2 + j) * 512]);
    }
  };

  f32x4 acc[4][8];
  #pragma unroll
  for (int mi = 0; mi < 4; ++mi)
    #pragma unroll
    for (int ni = 0; ni < 8; ++ni) acc[mi][ni] = f32x4{0.f, 0.f, 0.f, 0.f};

  dma(0, 0);
  for (int it = 0; it < 16; ++it) {
    __syncthreads();                       // drains DMA(it) + prev iter's frag reads
    if (it < 15) dma(it + 1, (it + 1) & 1);
    int buf = it & 1;
    short8 bf[8];
    #pragma unroll
    for (int ni = 0; ni < 8; ++ni) {
      int n = ni * 16 + lm;
      int gi = (n >> 1) * 8 + (((((n & 1) << 2) | qd) ^ ((n >> 1) & 7)));
      bf[ni] = *(const short8*)&Bs[buf][gi * 8];
    }
    #pragma unroll
    for (int mi = 0; mi < 4; ++mi) {
      int m = w * 64 + mi * 16 + lm;
      int gi = (m >> 1) * 8 + (((((m & 1) << 2) | qd) ^ ((m >> 1) & 7)));
      short8 af = *(const short8*)&As[buf][gi * 8];
      #pragma unroll
      for (int ni = 0; ni < 8; ++ni)
        acc[mi][ni] = __builtin_amdgcn_mfma_f32_16x16x32_bf16(af, bf[ni], acc[mi][ni], 0, 0, 0);
    }
  }

  // epilogue: out[b,h,v] += sum_rows wn[b,h,s] * tanh(acc + bv)
  int head0 = ct * 2;
  wlds[tid]       = wn[(((long)b * 16 + head0 + (tid >> 8)) << 12) + rt * 256 + (tid & 255)];
  wlds[tid + 256] = wn[(((long)b * 16 + head0 + ((tid + 256) >> 8)) << 12) + rt * 256 + ((tid + 256) & 255)];
  __syncthreads();

  float bias[8];
  #pragma unroll
  for (int ni = 0; ni < 8; ++ni) bias[ni] = bv[(head0 + (ni >> 2)) * 64 + (ni & 3) * 16 + lm];
  float res[8] = {0.f, 0.f, 0.f, 0.f, 0.f, 0.f, 0.f, 0.f};
  #pragma unroll
  for (int mi = 0; mi < 4; ++mi) {
    int rb = w * 64 + mi * 16 + qd * 4;
    #pragma unroll
    for (int h = 0; h < 2; ++h) {
      float w0 = wlds[h * 256 + rb + 0];
      float w1 = wlds[h * 256 + rb + 1];
      float w2 = wlds[h * 256 + rb + 2];
      float w3 = wlds[h * 256 + rb + 3];
      #pragma unroll
      for (int nj = 0; nj < 4; ++nj) {
        int ni = h * 4 + nj;
        f32x4 c = acc[mi][ni];
        res[ni] += w0 * fast_tanh(c[0] + bias[ni]) + w1 * fast_tanh(c[1] + bias[ni])
                 + w2 * fast_tanh(c[2] + bias[ni]) + w3 * fast_tanh(c[3] + bias[ni]);
      }
    }
  }
  #pragma unroll
  for (int ni = 0; ni < 8; ++ni) {
    float v = res[ni];
    v += __shfl_xor(v, 16, 64);
    v += __shfl_xor(v, 32, 64);
    if (qd == 0)
      atomicAdd(&out[b * 1024 + (head0 + (ni >> 2)) * 64 + (ni & 3) * 16 + lm], v);
  }
}

// ---------- launch ----------
extern "C" void kernel_launch(void* const* d_in, const int* in_sizes, int n_in,
                              void* d_out, int out_size, void* d_ws, size_t ws_size,
                              hipStream_t stream) {
  const float* kv = (const float*)d_in[0];
  const float* Wk = (const float*)d_in[1];
  // d_in[2] = b_k : constant over softmax axis -> cancels, unused
  const float* Wv = (const float*)d_in[3];
  const float* bv = (const float*)d_in[4];
  const float* q  = (const float*)d_in[5];
  float* out = (float*)d_out;

  char* ws = (char*)d_ws;
  unsigned short* xb  = (unsigned short*)(ws);                       // 128 MB
  unsigned short* wqb = (unsigned short*)(ws + 134217728);           // 16 KB
  unsigned short* wvt = (unsigned short*)(ws + 134217728 + 16384);   // 1 MB
  float* dotbuf = (float*)(ws + 134217728 + 16384 + 1048576);        // 8 MB

  hipMemsetAsync(d_out, 0, 32768 * sizeof(float), stream);
  prep_kernel<<<160, 256, 0, stream>>>(Wk, q, Wv, wqb, wvt);
  dot_kernel<<<1024, 256, 0, stream>>>(kv, wqb, xb, dotbuf);
  softmax_kernel<<<512, 256, 0, stream>>>(dotbuf);
  out_gemm_kernel<<<4096, 256, 0, stream>>>(xb, wvt, dotbuf, bv, out);
}

// Round 4
// 563.294 us; speedup vs baseline: 1.1662x; 1.0272x over previous
//
#include <hip/hip_runtime.h>
#include <cstdint>

using short8 = __attribute__((ext_vector_type(8))) short;
using f32x4  = __attribute__((ext_vector_type(4))) float;

// ---------- helpers ----------
__device__ __forceinline__ unsigned short bf16rne(float f) {
  unsigned int u = __float_as_uint(f);
  unsigned int r = u + 0x7fffu + ((u >> 16) & 1u);
  return (unsigned short)(r >> 16);
}

__device__ __forceinline__ void gl2lds16(const void* g, void* s) {
  auto gp = reinterpret_cast<const __attribute__((address_space(1))) unsigned int*>(
      reinterpret_cast<uintptr_t>(g));
  auto sp = reinterpret_cast<__attribute__((address_space(3))) unsigned int*>(
      (uint32_t)reinterpret_cast<uintptr_t>(s));
  __builtin_amdgcn_global_load_lds(gp, sp, 16, 0, 0);
}

__device__ __forceinline__ float fast_tanh(float x) {
  float e = __expf(2.0f * x);
  return 1.0f - 2.0f / (e + 1.0f);
}

// ---------- K0: fold Wq = W_k @ q (bf16 [16][512]); Wvt = W_v^T (bf16 [1024][512]) ----------
__global__ __launch_bounds__(256) void prep_kernel(
    const float* __restrict__ Wk, const float* __restrict__ q,
    const float* __restrict__ Wv,
    unsigned short* __restrict__ wqb, unsigned short* __restrict__ wvt) {
  __shared__ float T[64 * 65];
  int bid = blockIdx.x;
  if (bid < 32) {
    int idx = bid * 256 + threadIdx.x;   // 0..8191
    int n = idx >> 9, c = idx & 511;
    const float* wrow = Wk + (long)c * 1024 + n * 64;
    const float* qrow = q + n * 64;
    float s = 0.f;
    #pragma unroll 8
    for (int k = 0; k < 64; ++k) s += wrow[k] * qrow[k];
    wqb[n * 512 + c] = bf16rne(s);
  } else {
    int t = bid - 32;                    // 0..127
    int tc = t & 7, tl = t >> 3;
    int c0 = tc * 64, l0 = tl * 64;
    int j = threadIdx.x & 63, i0 = threadIdx.x >> 6;
    #pragma unroll
    for (int ii = 0; ii < 16; ++ii) {
      int i = i0 * 16 + ii;
      T[i * 65 + j] = Wv[(long)(c0 + i) * 1024 + l0 + j];
    }
    __syncthreads();
    #pragma unroll
    for (int ii = 0; ii < 16; ++ii) {
      int jj = i0 * 16 + ii;
      wvt[(long)(l0 + jj) * 512 + c0 + j] = bf16rne(T[j * 65 + jj]);
    }
  }
}

// ---------- K2: fused cvt + dot, 1-barrier async pipeline (unchanged from R3) ----------
__global__ __launch_bounds__(256) void dot_kernel(
    const float* __restrict__ kv, const unsigned short* __restrict__ wqb,
    unsigned short* __restrict__ xb, float* __restrict__ dotbuf) {
  __shared__ __align__(16) float AsF[2][128 * 64];          // 2 x 32 KB
  __shared__ __align__(16) unsigned short Ws[16 * 512];     // 16 KB
  int tid = threadIdx.x, l = tid & 63, w = tid >> 6;
  long row0 = (long)blockIdx.x * 128;
  int qd = l >> 4, lm = l & 15;

  for (int j = 0; j < 4; ++j) {
    int n = w * 4 + j;
    gl2lds16(wqb + n * 512 + ((l ^ (n & 7)) * 8), &Ws[n * 512]);
  }

  auto dmaA = [&](int it, int buf) {
    #pragma unroll
    for (int j = 0; j < 8; ++j) {
      int g = (w * 8 + j) * 64 + l;
      int r = g >> 4, c = g & 15;
      int cc = c ^ (r & 14);
      gl2lds16(kv + (row0 + r) * 512 + it * 64 + cc * 4, &AsF[buf][(w * 8 + j) * 256]);
    }
  };

  f32x4 acc[2];
  acc[0] = f32x4{0.f, 0.f, 0.f, 0.f};
  acc[1] = f32x4{0.f, 0.f, 0.f, 0.f};

  dmaA(0, 0);
  for (int it = 0; it < 8; ++it) {
    __syncthreads();
    if (it < 7) dmaA(it + 1, (it + 1) & 1);
    const float* base = &AsF[it & 1][0];
    #pragma unroll
    for (int mi = 0; mi < 2; ++mi) {
      int m = w * 32 + mi * 16 + lm;
      int s = m & 14;
      #pragma unroll
      for (int k32 = 0; k32 < 2; ++k32) {
        int fc = k32 * 8 + qd * 2;
        float4 fa = *(const float4*)&base[(m * 16 + (fc ^ s)) * 4];
        float4 fb = *(const float4*)&base[(m * 16 + ((fc + 1) ^ s)) * 4];
        short8 h;
        h[0] = bf16rne(fa.x); h[1] = bf16rne(fa.y); h[2] = bf16rne(fa.z); h[3] = bf16rne(fa.w);
        h[4] = bf16rne(fb.x); h[5] = bf16rne(fb.y); h[6] = bf16rne(fb.z); h[7] = bf16rne(fb.w);
        *(short8*)&xb[(row0 + m) * 512 + it * 64 + k32 * 32 + qd * 8] = h;
        int cl = it * 8 + k32 * 4 + qd;
        short8 bfrag = *(const short8*)&Ws[lm * 512 + ((cl ^ (lm & 7)) * 8)];
        acc[mi] = __builtin_amdgcn_mfma_f32_16x16x32_bf16(h, bfrag, acc[mi], 0, 0, 0);
      }
    }
  }
  #pragma unroll
  for (int mi = 0; mi < 2; ++mi) {
    long rg = row0 + w * 32 + mi * 16 + qd * 4;
    long b = rg >> 12;
    long s = rg & 4095;
    *(f32x4*)&dotbuf[((b * 16 + lm) << 12) + s] = acc[mi];
  }
}

// ---------- K3: softmax over s per (b,n), normalize in place ----------
__global__ __launch_bounds__(256) void softmax_kernel(float* __restrict__ dotbuf) {
  long bn = blockIdx.x;
  float4* p = (float4*)(dotbuf + bn * 4096);
  int tid = threadIdx.x;
  int l = tid & 63, w = tid >> 6;
  float4 v[4];
  float mx = -1e30f;
  #pragma unroll
  for (int i = 0; i < 4; ++i) {
    v[i] = p[tid + i * 256];
    mx = fmaxf(mx, fmaxf(fmaxf(v[i].x, v[i].y), fmaxf(v[i].z, v[i].w)));
  }
  for (int o = 32; o; o >>= 1) mx = fmaxf(mx, __shfl_xor(mx, o, 64));
  __shared__ float redm[4];
  __shared__ float reds[4];
  if (l == 0) redm[w] = mx;
  __syncthreads();
  mx = fmaxf(fmaxf(redm[0], redm[1]), fmaxf(redm[2], redm[3]));
  float s = 0.f;
  #pragma unroll
  for (int i = 0; i < 4; ++i) {
    v[i].x = __expf(v[i].x - mx); v[i].y = __expf(v[i].y - mx);
    v[i].z = __expf(v[i].z - mx); v[i].w = __expf(v[i].w - mx);
    s += v[i].x + v[i].y + v[i].z + v[i].w;
  }
  for (int o = 32; o; o >>= 1) s += __shfl_xor(s, o, 64);
  if (l == 0) reds[w] = s;
  __syncthreads();
  s = reds[0] + reds[1] + reds[2] + reds[3];
  float inv = 1.0f / s;
  #pragma unroll
  for (int i = 0; i < 4; ++i) {
    v[i].x *= inv; v[i].y *= inv; v[i].z *= inv; v[i].w *= inv;
    p[tid + i * 256] = v[i];
  }
}

// ---------- K4: value GEMM + tanh + weighted reduce; 256x128 tile, 64x128/wave,
// BK=32 double-buffered, 1 barrier/iter, fully-unrolled K-loop with ALL address
// math hoisted (R3 was VALU-issue-bound at 52% recomputing swizzles per iter).
// LDS image identical to R3 (pair-line XOR swizzle, 0 bank conflicts). ----------
__global__ __launch_bounds__(256, 2) void out_gemm_kernel(
    const unsigned short* __restrict__ xb, const unsigned short* __restrict__ wvt,
    const float* __restrict__ wn, const float* __restrict__ bv,
    float* __restrict__ out) {
  __shared__ __align__(16) unsigned short As[2][8192];   // 2 x 256r x 32k
  __shared__ __align__(16) unsigned short Bs[2][4096];   // 2 x 128n x 32k
  __shared__ float wlds[512];
  int tid = threadIdx.x, l = tid & 63, w = tid >> 6;
  int qd = l >> 4, lm = l & 15;

  int id = blockIdx.x;                    // XCD swizzle: same (rt,b), all 8 ct -> same XCD
  int ct = (id >> 3) & 7;
  int g = (id & 7) | ((id >> 6) << 3);    // 0..511
  int rt = g & 15, b = g >> 4;
  long row0 = ((long)b << 12) + rt * 256;
  const unsigned short* Ag = xb + row0 * 512;
  const unsigned short* Bg = wvt + (long)ct * 128 * 512;
  int head0 = ct * 2;

  // ---- hoisted DMA source pointers (lane-swizzled) + LDS dests ----
  const unsigned short* pa[4];
  unsigned short* da[4];
  #pragma unroll
  for (int j = 0; j < 4; ++j) {
    int pl = (w * 4 + j) * 64 + l;
    int r2 = pl >> 3, sub = (pl & 7) ^ (r2 & 7);
    int r = r2 * 2 + (sub >> 2), c = sub & 3;
    pa[j] = Ag + r * 512 + c * 8;
    da[j] = &As[0][(w * 4 + j) * 512];
  }
  const unsigned short* pb[2];
  unsigned short* db[2];
  #pragma unroll
  for (int j = 0; j < 2; ++j) {
    int pl = (w * 2 + j) * 64 + l;
    int r2 = pl >> 3, sub = (pl & 7) ^ (r2 & 7);
    int r = r2 * 2 + (sub >> 2), c = sub & 3;
    pb[j] = Bg + r * 512 + c * 8;
    db[j] = &Bs[0][(w * 2 + j) * 512];
  }
  // ---- hoisted fragment LDS byte-offsets ----
  int ofsA[4], ofsB[8];
  #pragma unroll
  for (int mi = 0; mi < 4; ++mi) {
    int m = w * 64 + mi * 16 + lm;
    int gi = (m >> 1) * 8 + (((((m & 1) << 2) | qd) ^ ((m >> 1) & 7)));
    ofsA[mi] = gi * 16;
  }
  #pragma unroll
  for (int ni = 0; ni < 8; ++ni) {
    int n = ni * 16 + lm;
    int gi = (n >> 1) * 8 + (((((n & 1) << 2) | qd) ^ ((n >> 1) & 7)));
    ofsB[ni] = gi * 16;
  }

  // epilogue weights: load early (visibility guaranteed by the loop's barriers)
  wlds[tid]       = wn[(((long)b * 16 + head0 + (tid >> 8)) << 12) + rt * 256 + (tid & 255)];
  wlds[tid + 256] = wn[(((long)b * 16 + head0 + ((tid + 256) >> 8)) << 12) + rt * 256 + ((tid + 256) & 255)];

  f32x4 acc[4][8];
  #pragma unroll
  for (int mi = 0; mi < 4; ++mi)
    #pragma unroll
    for (int ni = 0; ni < 8; ++ni) acc[mi][ni] = f32x4{0.f, 0.f, 0.f, 0.f};

  // prologue DMA iter 0 -> buf 0
  #pragma unroll
  for (int j = 0; j < 4; ++j) { gl2lds16(pa[j], da[j]); pa[j] += 32; }
  #pragma unroll
  for (int j = 0; j < 2; ++j) { gl2lds16(pb[j], db[j]); pb[j] += 32; }

  const char* cAs = (const char*)&As[0][0];
  const char* cBs = (const char*)&Bs[0][0];

  #pragma unroll
  for (int it = 0; it < 16; ++it) {
    __syncthreads();                       // drains DMA(it) + prev iter's frag reads
    if (it < 15) {
      int nb = (it + 1) & 1;               // compile-time under full unroll
      #pragma unroll
      for (int j = 0; j < 4; ++j) { gl2lds16(pa[j], da[j] + nb * 8192); pa[j] += 32; }
      #pragma unroll
      for (int j = 0; j < 2; ++j) { gl2lds16(pb[j], db[j] + nb * 4096); pb[j] += 32; }
    }
    int bo = (it & 1) * 16384, bo2 = (it & 1) * 8192;   // fold into ds_read imm
    short8 bf[8];
    #pragma unroll
    for (int ni = 0; ni < 8; ++ni) bf[ni] = *(const short8*)(cBs + bo2 + ofsB[ni]);
    #pragma unroll
    for (int mi = 0; mi < 4; ++mi) {
      short8 af = *(const short8*)(cAs + bo + ofsA[mi]);
      #pragma unroll
      for (int ni = 0; ni < 8; ++ni)
        acc[mi][ni] = __builtin_amdgcn_mfma_f32_16x16x32_bf16(af, bf[ni], acc[mi][ni], 0, 0, 0);
    }
  }

  // epilogue: out[b,h,v] += sum_rows wn[b,h,s] * tanh(acc + bv)
  __syncthreads();   // wlds visible (already was via loop barriers; belt-and-braces)

  float bias[8];
  #pragma unroll
  for (int ni = 0; ni < 8; ++ni) bias[ni] = bv[(head0 + (ni >> 2)) * 64 + (ni & 3) * 16 + lm];
  float res[8] = {0.f, 0.f, 0.f, 0.f, 0.f, 0.f, 0.f, 0.f};
  #pragma unroll
  for (int mi = 0; mi < 4; ++mi) {
    int rb = w * 64 + mi * 16 + qd * 4;
    #pragma unroll
    for (int h = 0; h < 2; ++h) {
      float w0 = wlds[h * 256 + rb + 0];
      float w1 = wlds[h * 256 + rb + 1];
      float w2 = wlds[h * 256 + rb + 2];
      float w3 = wlds[h * 256 + rb + 3];
      #pragma unroll
      for (int nj = 0; nj < 4; ++nj) {
        int ni = h * 4 + nj;
        f32x4 c = acc[mi][ni];
        res[ni] += w0 * fast_tanh(c[0] + bias[ni]) + w1 * fast_tanh(c[1] + bias[ni])
                 + w2 * fast_tanh(c[2] + bias[ni]) + w3 * fast_tanh(c[3] + bias[ni]);
      }
    }
  }
  #pragma unroll
  for (int ni = 0; ni < 8; ++ni) {
    float v = res[ni];
    v += __shfl_xor(v, 16, 64);
    v += __shfl_xor(v, 32, 64);
    if (qd == 0)
      atomicAdd(&out[b * 1024 + (head0 + (ni >> 2)) * 64 + (ni & 3) * 16 + lm], v);
  }
}

// ---------- launch ----------
extern "C" void kernel_launch(void* const* d_in, const int* in_sizes, int n_in,
                              void* d_out, int out_size, void* d_ws, size_t ws_size,
                              hipStream_t stream) {
  const float* kv = (const float*)d_in[0];
  const float* Wk = (const float*)d_in[1];
  // d_in[2] = b_k : constant over softmax axis -> cancels, unused
  const float* Wv = (const float*)d_in[3];
  const float* bv = (const float*)d_in[4];
  const float* q  = (const float*)d_in[5];
  float* out = (float*)d_out;

  char* ws = (char*)d_ws;
  unsigned short* xb  = (unsigned short*)(ws);                       // 128 MB
  unsigned short* wqb = (unsigned short*)(ws + 134217728);           // 16 KB
  unsigned short* wvt = (unsigned short*)(ws + 134217728 + 16384);   // 1 MB
  float* dotbuf = (float*)(ws + 134217728 + 16384 + 1048576);        // 8 MB

  hipMemsetAsync(d_out, 0, 32768 * sizeof(float), stream);
  prep_kernel<<<160, 256, 0, stream>>>(Wk, q, Wv, wqb, wvt);
  dot_kernel<<<1024, 256, 0, stream>>>(kv, wqb, xb, dotbuf);
  softmax_kernel<<<512, 256, 0, stream>>>(dotbuf);
  out_gemm_kernel<<<4096, 256, 0, stream>>>(xb, wvt, dotbuf, bv, out);
}